// Round 7
// baseline (22.522 us; speedup 1.0000x reference)
//
#include <hip/hip_runtime.h>

#define Nn 4096
#define NTRI 528              // 32*33/2 upper-tri 128x128 tiles
#define NTILE 2080            // 2*528 + 1024
#define NGRID 512             // 2 blocks/CU -> single dispatch batch

typedef __attribute__((ext_vector_type(4))) float f32x4;

#define C_K   0.7213475204444817f   // log2(e)/mu, mu=2
#define C_2K  1.4426950408889634f   // 2*log2(e)/mu
#define SKIP_BOUND -40.0f           // exp2(-40)*16.7M*beta ~ 1e-19 << 1e-5 threshold

// manual f32 -> fp8 e4m3fn (RNE, FTZ below 2^-6, saturate to 448)
__device__ __forceinline__ unsigned int f2e4m3(float f) {
  unsigned u = __float_as_uint(f);
  unsigned s = (u >> 24) & 0x80u;
  int e = (int)((u >> 23) & 0xff);
  unsigned m = u & 0x7fffffu;
  if (e < 121) return s;                         // FTZ (|x| < 2^-6), incl. zero
  unsigned mr = m + 0x7ffffu + ((m >> 20) & 1u); // RNE to 3 mantissa bits
  if (mr & 0x800000u) { mr = 0; e += 1; }
  int code = ((e - 120) << 3) | (int)(mr >> 20);
  if (code > 0x7e) code = 0x7e;                  // clamp to 448 (no inf/nan)
  return s | (unsigned)code;
}

__device__ __forceinline__ void gload_lds16(const void* g, void* l) {
  __builtin_amdgcn_global_load_lds(
      (const __attribute__((address_space(1))) unsigned int*)g,
      (__attribute__((address_space(3))) unsigned int*)l, 16, 0, 0);
}

// ---- prep: fp8 cast + prescaled norms kn[row] = -K * ||row||^2 --------------
__global__ __launch_bounds__(256) void prep_kernel(const float* __restrict__ X,
                                                   const float* __restrict__ Y,
                                                   float* __restrict__ kn,
                                                   unsigned char* __restrict__ Xq,
                                                   unsigned char* __restrict__ Yq) {
  int wave = threadIdx.x >> 6;
  int lane = threadIdx.x & 63;
  int row = blockIdx.x * 4 + wave;            // 0..8191
  const float* src;
  unsigned char* dst;
  if (row < Nn) { src = X + (size_t)row * 128;        dst = Xq + (size_t)row * 128; }
  else          { src = Y + (size_t)(row - Nn) * 128; dst = Yq + (size_t)(row - Nn) * 128; }
  float2 v = reinterpret_cast<const float2*>(src)[lane];
  float s = v.x * v.x + v.y * v.y;
#pragma unroll
  for (int off = 32; off > 0; off >>= 1) s += __shfl_xor(s, off);
  unsigned short h = (unsigned short)(f2e4m3(v.x) | (f2e4m3(v.y) << 8));
  reinterpret_cast<unsigned short*>(dst)[lane] = h;
  if (lane == 0) kn[row] = -C_K * s;
}

// ---- persistent fused pairwise-exp-sum, cross-tile pipelined -----------------
// tile id t: t<528 -> q=0 (XX upper-tri); t<1056 -> q=1 (YY upper-tri);
// else q=2 (XY full). Block b handles t = b, b+512, ... (4 or 5 tiles).
// LDS: 2 x (As 16KB | Bs 16KB) fp8 double buffer. Per tile ONE __syncthreads:
//   COMPUTE(buf) ; barrier ; STAGE(t+2 -> buf) ; EPILOGUE(t)
// At the barrier only stage(t+1)'s 8 loads/wave are outstanding and they flew
// under COMPUTE's MFMA, so the implicit vmcnt(0) drain is already satisfied.
// fp8 layout (HW-verified r6): row r = 8 x 16B units, logical unit u stored at
// physical p = u ^ (r&7); DMA source pre-swizzled per-lane, LDS dest linear.
__global__ __launch_bounds__(256, 2) void mmd_main(const unsigned char* __restrict__ Xq,
                                                   const unsigned char* __restrict__ Yq,
                                                   const float* __restrict__ kn,
                                                   float* __restrict__ partials) {
  __shared__ __align__(16) char lds[65536];

  const int b = blockIdx.x;
  const int T = (b + 4 * NGRID < NTILE) ? 5 : 4;

  const int lane = threadIdx.x & 63;
  const int wv   = threadIdx.x >> 6;
  const int wr = wv >> 1, wc = wv & 1;    // 2x2 wave grid, 64x64 per wave
  const int lr = lane & 15, kq = lane >> 4;

  // stage-side lane constants
  const int rg = lane >> 3;               // row within 8-row group
  const int uu = (lane & 7) ^ (rg & 7);   // logical unit this lane fetches
  const int lane16 = lane << 4;

  float bsum = 0.f;                       // per-thread across tiles (w folded)

  // decode tile id -> quadrant + block coords
  auto decode = [&](int t, int& q, int& bx, int& by) {
    if (t < 2 * NTRI) {
      q = (t >= NTRI) ? 1 : 0;
      const int u = t - q * NTRI;
      int r = (int)((sqrtf(8.f * (float)u + 1.f) - 1.f) * 0.5f);
      while ((r + 1) * (r + 2) / 2 <= u) ++r;
      while (r * (r + 1) / 2 > u) --r;
      bx = r; by = u - r * (r + 1) / 2;   // by <= bx
    } else {
      q = 2;
      const int u = t - 2 * NTRI;
      by = u >> 5; bx = u & 31;
    }
  };

  auto stage = [&](int t, char* base) {
    int q, bx, by; decode(t, q, bx, by);
    const unsigned char* Asrc = (q == 1) ? Yq : Xq;
    const unsigned char* Bsrc = (q == 0) ? Xq : Yq;
    const char* Ag = (const char*)Asrc + ((size_t)((by << 7) + (wv << 5) + rg) << 7) + (uu << 4);
    const char* Bg = (const char*)Bsrc + ((size_t)((bx << 7) + (wv << 5) + rg) << 7) + (uu << 4);
    char* dA = base + (wv << 12);
    char* dB = base + 16384 + (wv << 12);
#pragma unroll
    for (int i = 0; i < 4; ++i) {         // 4 x 8-row groups = 32 rows per wave
      gload_lds16(Ag + (i << 10), dA + (i << 10));
      gload_lds16(Bg + (i << 10), dB + (i << 10));
    }
  };

  // prologue: fill both buffers (T >= 4 always)
  stage(b, lds);
  stage(b + NGRID, lds + 32768);
  __syncthreads();

  for (int i = 0; i < T; ++i) {
    const int t = b + i * NGRID;
    char* base = lds + ((i & 1) << 15);

    // ---- COMPUTE: 4 k-steps of 32 (fp8), 16 fragments per wave --------------
    f32x4 acc[4][4];
#pragma unroll
    for (int m = 0; m < 4; ++m)
#pragma unroll
      for (int n = 0; n < 4; ++n)
        acc[m][n] = (f32x4){0.f, 0.f, 0.f, 0.f};

#pragma unroll
    for (int ks = 0; ks < 4; ++ks) {
      const int uf = (ks << 1) + (kq >> 1);  // logical 16B unit of this frag
      const int hb = (kq & 1) << 3;          // 8B half within the unit
      long a[4], bfr[4];
#pragma unroll
      for (int m = 0; m < 4; ++m) {
        const int row = (wr << 6) + (m << 4) + lr;
        a[m] = *reinterpret_cast<const long*>(base + (row << 7) + ((uf ^ (lr & 7)) << 4) + hb);
      }
#pragma unroll
      for (int n = 0; n < 4; ++n) {
        const int row = (wc << 6) + (n << 4) + lr;
        bfr[n] = *reinterpret_cast<const long*>(base + 16384 + (row << 7) + ((uf ^ (lr & 7)) << 4) + hb);
      }
#pragma unroll
      for (int m = 0; m < 4; ++m)
#pragma unroll
        for (int n = 0; n < 4; ++n)
          acc[m][n] = __builtin_amdgcn_mfma_f32_16x16x32_fp8_fp8(a[m], bfr[n], acc[m][n], 0, 0, 0);
    }

    __syncthreads();                     // all waves done reading buf (i&1)

    if (i + 2 < T) stage(b + (i + 2) * NGRID, base);   // prefetch 2-ahead

    // ---- EPILOGUE(t): wave-level underflow skip, then exp2 ------------------
    int q, bx, by; decode(t, q, bx, by);
    const float* knA = (q == 1) ? kn + Nn : kn;
    const float* knB = (q == 0) ? kn : kn + Nn;
    const int R0 = by << 7, C0 = bx << 7;
    const bool diagblk = (q < 2) && (bx == by);

    f32x4 ax[4];
    float cy[4];
#pragma unroll
    for (int m = 0; m < 4; ++m)
      ax[m] = *reinterpret_cast<const f32x4*>(knA + R0 + (wr << 6) + (m << 4) + (kq << 2));
#pragma unroll
    for (int n = 0; n < 4; ++n)
      cy[n] = knB[C0 + (wc << 6) + (n << 4) + lr];

    f32x4 vm = acc[0][0];
#pragma unroll
    for (int m = 0; m < 4; ++m)
#pragma unroll
      for (int n = 0; n < 4; ++n) {
        if (m == 0 && n == 0) continue;
        vm[0] = fmaxf(vm[0], acc[m][n][0]);
        vm[1] = fmaxf(vm[1], acc[m][n][1]);
        vm[2] = fmaxf(vm[2], acc[m][n][2]);
        vm[3] = fmaxf(vm[3], acc[m][n][3]);
      }
    float amax = fmaxf(fmaxf(vm[0], vm[1]), fmaxf(vm[2], vm[3]));
    float axm = -1e30f;
#pragma unroll
    for (int m = 0; m < 4; ++m)
      axm = fmaxf(axm, fmaxf(fmaxf(ax[m][0], ax[m][1]), fmaxf(ax[m][2], ax[m][3])));
    float cym = fmaxf(fmaxf(cy[0], cy[1]), fmaxf(cy[2], cy[3]));
    float bound = fmaf(amax, C_2K, axm + cym);

    if (__any(bound > SKIP_BOUND)) {
      float l0 = 0.f, l1 = 0.f, l2 = 0.f, l3 = 0.f;
#pragma unroll
      for (int m = 0; m < 4; ++m) {
        const int rbase = (wr << 6) + (m << 4) + (kq << 2);
#pragma unroll
        for (int n = 0; n < 4; ++n) {
          const float e0 = __builtin_amdgcn_exp2f(fmaf(acc[m][n][0], C_2K, ax[m][0] + cy[n]));
          const float e1 = __builtin_amdgcn_exp2f(fmaf(acc[m][n][1], C_2K, ax[m][1] + cy[n]));
          const float e2 = __builtin_amdgcn_exp2f(fmaf(acc[m][n][2], C_2K, ax[m][2] + cy[n]));
          const float e3 = __builtin_amdgcn_exp2f(fmaf(acc[m][n][3], C_2K, ax[m][3] + cy[n]));
          if (diagblk) {
            const int cc = (wc << 6) + (n << 4) + lr;
            if (rbase + 0 != cc) l0 += e0;
            if (rbase + 1 != cc) l1 += e1;
            if (rbase + 2 != cc) l2 += e2;
            if (rbase + 3 != cc) l3 += e3;
          } else {
            l0 += e0; l1 += e1; l2 += e2; l3 += e3;
          }
        }
      }
      float w;
      if (q < 2) w = ((bx == by) ? 1.f : 2.f) * (1.0f / 16773120.0f);  // alpha
      else       w = -2.0f / 16777216.0f;                               // -2*beta
      bsum = fmaf((l0 + l1) + (l2 + l3), w, bsum);
    }
  }

  // ---- block reduction (once, after all tiles) --------------------------------
#pragma unroll
  for (int off = 32; off > 0; off >>= 1) bsum += __shfl_xor(bsum, off);
  __syncthreads();                              // lds free for reuse
  float* red = reinterpret_cast<float*>(lds);
  if (lane == 0) red[wv] = bsum;
  __syncthreads();
  if (threadIdx.x == 0)
    partials[b] = (red[0] + red[1]) + (red[2] + red[3]);
}

// ---- deterministic final reduction ------------------------------------------
__global__ __launch_bounds__(256) void mmd_final(const float* __restrict__ partials,
                                                 float* __restrict__ out) {
  float v = 0.f;
  for (int i = threadIdx.x; i < NGRID; i += 256) v += partials[i];
#pragma unroll
  for (int off = 32; off > 0; off >>= 1) v += __shfl_xor(v, off);
  __shared__ float red[4];
  if ((threadIdx.x & 63) == 0) red[threadIdx.x >> 6] = v;
  __syncthreads();
  if (threadIdx.x == 0) {
    // analytic diagonal: n*(alpha1+alpha2) = 2/4095
    out[0] = ((red[0] + red[1]) + (red[2] + red[3])) + (float)(2.0 / 4095.0);
  }
}

extern "C" void kernel_launch(void* const* d_in, const int* in_sizes, int n_in,
                              void* d_out, int out_size, void* d_ws, size_t ws_size,
                              hipStream_t stream) {
  const float* X = (const float*)d_in[0];
  const float* Y = (const float*)d_in[1];
  float* kn       = (float*)d_ws;                       // 8192 floats (-K*norm^2)
  float* partials = kn + 8192;                          // 512 floats
  unsigned char* Xq = (unsigned char*)(partials + 512); // 4096*128 fp8 (16B-aligned)
  unsigned char* Yq = Xq + (size_t)Nn * 128;
  float* out = (float*)d_out;

  hipLaunchKernelGGL(prep_kernel, dim3(2048), dim3(256), 0, stream, X, Y, kn, Xq, Yq);
  hipLaunchKernelGGL(mmd_main, dim3(NGRID), dim3(256), 0, stream, Xq, Yq, kn, partials);
  hipLaunchKernelGGL(mmd_final, dim3(1), dim3(256), 0, stream, partials, out);
}